// Round 1
// baseline (1923.334 us; speedup 1.0000x reference)
//
#include <hip/hip_runtime.h>

#define GAS __attribute__((address_space(1)))
#define LAS __attribute__((address_space(3)))

typedef __attribute__((ext_vector_type(8))) short bf16x8;
typedef __attribute__((ext_vector_type(4))) float f32x4;

static constexpr int Bb = 16, Ll = 2048, Hh = 512, Vv = 32000, H2 = 1024;
static constexpr int Mtot = Bb * Ll;  // 32768
static constexpr float LRc = 0.01f, EPSc = 1e-5f;

// ---- ws layout (bytes) ----
static constexpr size_t OFF_X    = 0;                                   // Mtot*Hh*4   = 67,108,864
static constexpr size_t OFF_EBF  = OFF_X   + (size_t)Mtot * Hh * 4;     // Vv*Hh*2     = 32,768,000
static constexpr size_t OFF_W1BF = OFF_EBF + (size_t)Vv * Hh * 2;       // H2*Hh*2
static constexpr size_t OFF_W2BF = OFF_W1BF + (size_t)H2 * Hh * 2;      // Hh*H2*2
static constexpr size_t OFF_CTX  = OFF_W2BF + (size_t)Hh * H2 * 2;      // Bb*Hh*4
static constexpr size_t OFF_FF1  = OFF_CTX + (size_t)Bb * Hh * 4;       // chunk of ff1 (bf16)

__device__ inline unsigned short f2bf(float f) {  // RNE f32 -> bf16
  unsigned u = __float_as_uint(f);
  return (unsigned short)((u + 0x7fffu + ((u >> 16) & 1u)) >> 16);
}

// ---------------- f32 -> bf16 conversion ----------------
__global__ __launch_bounds__(256) void cvt_bf16_kernel(const float* __restrict__ src,
                                                       unsigned short* __restrict__ dst, int n8) {
  int stride = gridDim.x * blockDim.x;
  for (int i = blockIdx.x * blockDim.x + threadIdx.x; i < n8; i += stride) {
    const float4* p = (const float4*)(src + (size_t)i * 8);
    float4 a = p[0], b = p[1];
    uint4 o;
    o.x = f2bf(a.x) | ((unsigned)f2bf(a.y) << 16);
    o.y = f2bf(a.z) | ((unsigned)f2bf(a.w) << 16);
    o.z = f2bf(b.x) | ((unsigned)f2bf(b.y) << 16);
    o.w = f2bf(b.z) | ((unsigned)f2bf(b.w) << 16);
    *(uint4*)(dst + (size_t)i * 8) = o;
  }
}

// ---------------- bf16 GEMM, B^T layout, 128x128 tile, BK=32 (m97 structure) ----------------
// out[m,n] = act( sum_k A[m,k]*Bmat[n,k] + bias[n] )
// GATHER: A row m sourced from Abase + seq[seq_off+m]*KTOT  (per-lane global addr into global_load_lds)
template <int KTOT, bool GATHER, bool RELUOUT>
__global__ __launch_bounds__(256) void gemm_bt(const unsigned short* __restrict__ Abase,
                                               const int* __restrict__ seq, int seq_off,
                                               const unsigned short* __restrict__ Bmat,
                                               const float* __restrict__ bias,
                                               unsigned short* __restrict__ outb,
                                               float* __restrict__ outf,
                                               int out_row_off, int ldout) {
  __shared__ unsigned short As[128 * 32];
  __shared__ unsigned short Bs[128 * 32];
  __shared__ unsigned long long aoff[128];
  const int tid = threadIdx.x;
  const int m0 = blockIdx.x * 128, n0 = blockIdx.y * 128;

  if (tid < 128) {
    long long r;
    if (GATHER) r = (long long)seq[seq_off + m0 + tid] * KTOT;
    else        r = (long long)(m0 + tid) * KTOT;
    aoff[tid] = (unsigned long long)r;
  }
  __syncthreads();

  const int srow = tid >> 2;         // staging row 0..63 (+i*64)
  const int scol = (tid & 3) * 8;    // staging col (elements)
  const int wave = tid >> 6;
  const int lane = tid & 63;
  const int wr = wave >> 1, wc = wave & 1;
  const int fr = lane & 15;
  const int fk = (lane >> 4) * 8;

  f32x4 acc[4][4] = {};

  for (int k0 = 0; k0 < KTOT; k0 += 32) {
#pragma unroll
    for (int i = 0; i < 2; ++i) {
      const unsigned short* ga = Abase + aoff[i * 64 + srow] + k0 + scol;
      __builtin_amdgcn_global_load_lds((const GAS void*)ga,
          (LAS void*)((char*)As + i * 4096 + wave * 1024), 16, 0, 0);
      const unsigned short* gb = Bmat + (size_t)(n0 + i * 64 + srow) * KTOT + k0 + scol;
      __builtin_amdgcn_global_load_lds((const GAS void*)gb,
          (LAS void*)((char*)Bs + i * 4096 + wave * 1024), 16, 0, 0);
    }
    __syncthreads();
    bf16x8 af[4], bfr[4];
#pragma unroll
    for (int m = 0; m < 4; ++m)
      af[m] = *(const bf16x8*)&As[(wr * 64 + m * 16 + fr) * 32 + fk];
#pragma unroll
    for (int n = 0; n < 4; ++n)
      bfr[n] = *(const bf16x8*)&Bs[(wc * 64 + n * 16 + fr) * 32 + fk];
#pragma unroll
    for (int m = 0; m < 4; ++m)
#pragma unroll
      for (int n = 0; n < 4; ++n)
        acc[m][n] = __builtin_amdgcn_mfma_f32_16x16x32_bf16(af[m], bfr[n], acc[m][n], 0, 0, 0);
    __syncthreads();
  }

  float bv[4];
#pragma unroll
  for (int n = 0; n < 4; ++n) bv[n] = bias[n0 + wc * 64 + n * 16 + fr];
#pragma unroll
  for (int m = 0; m < 4; ++m) {
#pragma unroll
    for (int n = 0; n < 4; ++n) {
#pragma unroll
      for (int j = 0; j < 4; ++j) {
        int rl = wr * 64 + m * 16 + ((lane >> 4) << 2) + j;
        int col = n0 + wc * 64 + n * 16 + fr;
        float v = acc[m][n][j] + bv[n];
        size_t off = (size_t)(out_row_off + m0 + rl) * ldout + col;
        if (RELUOUT) { v = fmaxf(v, 0.f); outb[off] = f2bf(v); }
        else outf[off] = v;
      }
    }
  }
}

// ---------------- residual add + LayerNorm (one wave per row, in-place on xbuf) ----------------
__global__ __launch_bounds__(256) void ln_kernel(float* __restrict__ xbuf,
                                                 const float* __restrict__ embed,
                                                 const int* __restrict__ seq,
                                                 const float* __restrict__ lnw,
                                                 const float* __restrict__ lnb) {
  int row = blockIdx.x * 4 + (threadIdx.x >> 6);
  int lane = threadIdx.x & 63;
  int c = lane * 8;
  int s = seq[row];
  float* xr = xbuf + (size_t)row * Hh;
  const float* hr = embed + (size_t)s * Hh;
  float4 f0 = *(const float4*)(xr + c), f1 = *(const float4*)(xr + c + 4);
  float4 h0 = *(const float4*)(hr + c), h1 = *(const float4*)(hr + c + 4);
  float x[8] = {f0.x + h0.x, f0.y + h0.y, f0.z + h0.z, f0.w + h0.w,
                f1.x + h1.x, f1.y + h1.y, f1.z + h1.z, f1.w + h1.w};
  float sm = 0.f, sq = 0.f;
#pragma unroll
  for (int u = 0; u < 8; ++u) { sm += x[u]; sq += x[u] * x[u]; }
#pragma unroll
  for (int m = 1; m < 64; m <<= 1) { sm += __shfl_xor(sm, m, 64); sq += __shfl_xor(sq, m, 64); }
  float mu = sm * (1.f / 512.f);
  float var = sq * (1.f / 512.f) - mu * mu;
  float rs = rsqrtf(var + EPSc);
  float y[8];
#pragma unroll
  for (int u = 0; u < 8; ++u) y[u] = (x[u] - mu) * rs * lnw[c + u] + lnb[c + u];
  *(float4*)(xr + c) = make_float4(y[0], y[1], y[2], y[3]);
  *(float4*)(xr + c + 4) = make_float4(y[4], y[5], y[6], y[7]);
}

// ---------------- TTT scan: 16 blocks x 512 threads; wave w owns w1-row j=w; thread owns w2-row i=tid ----------------
__global__ __launch_bounds__(512) void ttt_kernel(const float* __restrict__ hidden,
                                                  const float* __restrict__ w1_0,
                                                  const float* __restrict__ b1_0,
                                                  const float* __restrict__ w2_0,
                                                  const float* __restrict__ b2_0,
                                                  float* __restrict__ ctx) {
  const int b = blockIdx.x;
  const int tid = threadIdx.x;
  const int w = tid >> 6, lane = tid & 63;
  const int cl = lane * 8;
  const float* hb = hidden + (size_t)b * Ll * Hh;
  __shared__ float zb[8];
  __shared__ float dhp[8][8];

  float W1[8], W2[8];
#pragma unroll
  for (int u = 0; u < 8; ++u) W1[u] = w1_0[w * 512 + cl + u];
#pragma unroll
  for (int j = 0; j < 8; ++j) W2[j] = w2_0[tid * 8 + j];
  float B1w = b1_0[w];
  float B2i = b2_0[tid];

  float K[8], Vi;
  {
    const float4* p = (const float4*)(hb + cl);
    float4 a = p[0], c4 = p[1];
    K[0] = a.x; K[1] = a.y; K[2] = a.z; K[3] = a.w;
    K[4] = c4.x; K[5] = c4.y; K[6] = c4.z; K[7] = c4.w;
    Vi = hb[512 + tid];
  }
  const float scale = 2.0f / 512.0f;

  for (int t = 0; t < 1023; ++t) {
    float KN[8], VN;
    if (t < 1022) {  // prefetch next (k,v)
      const float4* p = (const float4*)(hb + (size_t)(2 * t + 2) * 512 + cl);
      float4 a = p[0], c4 = p[1];
      KN[0] = a.x; KN[1] = a.y; KN[2] = a.z; KN[3] = a.w;
      KN[4] = c4.x; KN[5] = c4.y; KN[6] = c4.z; KN[7] = c4.w;
      VN = hb[(size_t)(2 * t + 3) * 512 + tid];
    }
    // z_w = w1[w,:] @ k  (wave reduce)
    float zp = 0.f;
#pragma unroll
    for (int u = 0; u < 8; ++u) zp = fmaf(W1[u], K[u], zp);
#pragma unroll
    for (int m = 1; m < 64; m <<= 1) zp += __shfl_xor(zp, m, 64);
    float zw = zp + B1w;
    if (lane == 0) zb[w] = zw;
    __syncthreads();
    float hj[8];
#pragma unroll
    for (int j = 0; j < 8; ++j) hj[j] = fmaxf(zb[j], 0.f);
    float pred = B2i;
#pragma unroll
    for (int j = 0; j < 8; ++j) pred = fmaf(W2[j], hj[j], pred);
    float d = (pred - Vi) * scale;
    // dh partials from OLD w2
    float dp[8];
#pragma unroll
    for (int j = 0; j < 8; ++j) dp[j] = W2[j] * d;
#pragma unroll
    for (int m = 1; m < 64; m <<= 1) {
#pragma unroll
      for (int j = 0; j < 8; ++j) dp[j] += __shfl_xor(dp[j], m, 64);
    }
    if (lane == 0) {
#pragma unroll
      for (int j = 0; j < 8; ++j) dhp[w][j] = dp[j];
    }
    // w2 / b2 updates (use old d, hj)
#pragma unroll
    for (int j = 0; j < 8; ++j) W2[j] = fmaf(-LRc * d, hj[j], W2[j]);
    B2i -= LRc * d;
    __syncthreads();
    float dhw = 0.f;
#pragma unroll
    for (int ww = 0; ww < 8; ++ww) dhw += dhp[ww][w];
    float dzw = (zw > 0.f) ? dhw : 0.f;
#pragma unroll
    for (int u = 0; u < 8; ++u) W1[u] = fmaf(-LRc * dzw, K[u], W1[u]);
    B1w -= LRc * dzw;
    if (t < 1022) {
#pragma unroll
      for (int u = 0; u < 8; ++u) K[u] = KN[u];
      Vi = VN;
    }
  }

  // query = hidden row L-1
  {
    const float4* p = (const float4*)(hb + (size_t)(Ll - 1) * 512 + cl);
    float4 a = p[0], c4 = p[1];
    K[0] = a.x; K[1] = a.y; K[2] = a.z; K[3] = a.w;
    K[4] = c4.x; K[5] = c4.y; K[6] = c4.z; K[7] = c4.w;
    float zp = 0.f;
#pragma unroll
    for (int u = 0; u < 8; ++u) zp = fmaf(W1[u], K[u], zp);
#pragma unroll
    for (int m = 1; m < 64; m <<= 1) zp += __shfl_xor(zp, m, 64);
    if (lane == 0) zb[w] = zp + B1w;
    __syncthreads();
    float pred = B2i;
#pragma unroll
    for (int j = 0; j < 8; ++j) pred = fmaf(W2[j], fmaxf(zb[j], 0.f), pred);
    ctx[b * 512 + tid] = pred;
  }
}

// ---------------- head: out[b,v] = ctx[b,:] @ out_w[v,:] + out_b[v] ----------------
__global__ __launch_bounds__(256) void out_kernel(const float* __restrict__ ctx,
                                                  const float* __restrict__ outw,
                                                  const float* __restrict__ outb_,
                                                  float* __restrict__ out) {
  __shared__ float cs[16 * 516];
  int tid = threadIdx.x;
#pragma unroll
  for (int r = 0; r < 32; ++r) {
    int idx = r * 256 + tid;
    cs[(idx >> 9) * 516 + (idx & 511)] = ctx[idx];
  }
  __syncthreads();
  int v = blockIdx.x * 16 + (tid >> 4);
  int b = tid & 15;
  const float4* wr = (const float4*)(outw + (size_t)v * 512);
  const float4* cr = (const float4*)(cs + b * 516);
  float acc = 0.f;
#pragma unroll 8
  for (int k = 0; k < 128; ++k) {
    float4 wv = wr[k];
    float4 cv = cr[k];
    acc += wv.x * cv.x + wv.y * cv.y + wv.z * cv.z + wv.w * cv.w;
  }
  out[(size_t)b * 32000 + v] = acc + outb_[v];
}

extern "C" void kernel_launch(void* const* d_in, const int* in_sizes, int n_in,
                              void* d_out, int out_size, void* d_ws, size_t ws_size,
                              hipStream_t stream) {
  const int*   seq    = (const int*)d_in[0];
  const float* embed  = (const float*)d_in[1];
  const float* enc_b1 = (const float*)d_in[3];
  const float* enc_b2 = (const float*)d_in[5];
  const float* ln_w   = (const float*)d_in[6];
  const float* ln_b   = (const float*)d_in[7];
  const float* mlp_w1 = (const float*)d_in[8];
  const float* mlp_b1 = (const float*)d_in[9];
  const float* mlp_w2 = (const float*)d_in[10];
  const float* mlp_b2 = (const float*)d_in[11];
  const float* out_w  = (const float*)d_in[12];
  const float* out_b  = (const float*)d_in[13];
  const float* enc_w1 = (const float*)d_in[2];
  const float* enc_w2 = (const float*)d_in[4];
  float* out = (float*)d_out;

  char* ws = (char*)d_ws;
  float*          xbuf = (float*)(ws + OFF_X);
  unsigned short* ebf  = (unsigned short*)(ws + OFF_EBF);
  unsigned short* w1bf = (unsigned short*)(ws + OFF_W1BF);
  unsigned short* w2bf = (unsigned short*)(ws + OFF_W2BF);
  float*          ctx  = (float*)(ws + OFF_CTX);
  unsigned short* ff1  = (unsigned short*)(ws + OFF_FF1);

  // adaptive ff1 chunking by available ws
  const int cand[4] = {1, 2, 4, 8};
  int nc = 8;
  for (int ci = 0; ci < 4; ++ci) {
    if (OFF_FF1 + (size_t)(Mtot / cand[ci]) * H2 * 2 <= ws_size) { nc = cand[ci]; break; }
  }

  cvt_bf16_kernel<<<2048, 256, 0, stream>>>(embed, ebf, Vv * Hh / 8);
  cvt_bf16_kernel<<<256, 256, 0, stream>>>(enc_w1, w1bf, H2 * Hh / 8);
  cvt_bf16_kernel<<<256, 256, 0, stream>>>(enc_w2, w2bf, Hh * H2 / 8);

  const int Mc = Mtot / nc;
  for (int c = 0; c < nc; ++c) {
    const int m0 = c * Mc;
    gemm_bt<512, true, true><<<dim3(Mc / 128, 8), 256, 0, stream>>>(
        ebf, seq, m0, w1bf, enc_b1, ff1, nullptr, 0, H2);
    gemm_bt<1024, false, false><<<dim3(Mc / 128, 4), 256, 0, stream>>>(
        ff1, nullptr, 0, w2bf, enc_b2, nullptr, xbuf, m0, Hh);
  }
  ln_kernel<<<Mtot / 4, 256, 0, stream>>>(xbuf, embed, seq, ln_w, ln_b);
  ttt_kernel<<<Bb, 512, 0, stream>>>(xbuf, mlp_w1, mlp_b1, mlp_w2, mlp_b2, ctx);
  out_kernel<<<Vv / 16, 256, 0, stream>>>(ctx, out_w, out_b, out);
}

// Round 2
// 1017.273 us; speedup vs baseline: 1.8907x; 1.8907x over previous
//
#include <hip/hip_runtime.h>

#define GAS __attribute__((address_space(1)))
#define LAS __attribute__((address_space(3)))

typedef __attribute__((ext_vector_type(8))) short bf16x8;
typedef __attribute__((ext_vector_type(4))) float f32x4;
typedef __attribute__((ext_vector_type(2))) float f32x2;

static constexpr int Bb = 16, Ll = 2048, Hh = 512, Vv = 32000, H2 = 1024;
static constexpr int Mtot = Bb * Ll;  // 32768
static constexpr float LRc = 0.01f, EPSc = 1e-5f;

// ---- ws layout (bytes) ----
static constexpr size_t OFF_X    = 0;                                   // Mtot*Hh*4
static constexpr size_t OFF_EBF  = OFF_X   + (size_t)Mtot * Hh * 4;     // Vv*Hh*2
static constexpr size_t OFF_W1BF = OFF_EBF + (size_t)Vv * Hh * 2;       // H2*Hh*2
static constexpr size_t OFF_W2BF = OFF_W1BF + (size_t)H2 * Hh * 2;      // Hh*H2*2
static constexpr size_t OFF_CTX  = OFF_W2BF + (size_t)Hh * H2 * 2;      // Bb*Hh*4
static constexpr size_t OFF_FF1  = OFF_CTX + (size_t)Bb * Hh * 4;       // chunk of ff1 (bf16)

__device__ inline unsigned short f2bf(float f) {  // RNE f32 -> bf16
  unsigned u = __float_as_uint(f);
  return (unsigned short)((u + 0x7fffu + ((u >> 16) & 1u)) >> 16);
}

// packed fp32 fma: d = a*b + c (element-wise on 2 floats, one VOP3P inst)
__device__ inline f32x2 pk_fma(f32x2 a, f32x2 b, f32x2 c) {
  f32x2 d;
  asm("v_pk_fma_f32 %0, %1, %2, %3" : "=v"(d) : "v"(a), "v"(b), "v"(c));
  return d;
}

// full-wave (64 lane) sum via DPP; result broadcast to all lanes via readlane.
#define DPP_ADD(ctrl)                                                        \
  {                                                                          \
    int t_ = __builtin_amdgcn_update_dpp(0, v_, ctrl, 0xf, 0xf, true);       \
    v_ = __float_as_int(__int_as_float(v_) + __int_as_float(t_));            \
  }
__device__ inline float wsum_bcast(float x) {
  int v_ = __float_as_int(x);
  DPP_ADD(0x111)  // row_shr:1
  DPP_ADD(0x112)  // row_shr:2
  DPP_ADD(0x114)  // row_shr:4
  DPP_ADD(0x118)  // row_shr:8  -> lane 15 of each row-of-16 has row sum
  DPP_ADD(0x142)  // row_bcast:15 -> lane31 = rows0+1, lane63 = rows2+3
  DPP_ADD(0x143)  // row_bcast:31 -> lane63 = total
  return __int_as_float(__builtin_amdgcn_readlane(v_, 63));
}

// ---------------- f32 -> bf16 conversion ----------------
__global__ __launch_bounds__(256) void cvt_bf16_kernel(const float* __restrict__ src,
                                                       unsigned short* __restrict__ dst, int n8) {
  int stride = gridDim.x * blockDim.x;
  for (int i = blockIdx.x * blockDim.x + threadIdx.x; i < n8; i += stride) {
    const float4* p = (const float4*)(src + (size_t)i * 8);
    float4 a = p[0], b = p[1];
    uint4 o;
    o.x = f2bf(a.x) | ((unsigned)f2bf(a.y) << 16);
    o.y = f2bf(a.z) | ((unsigned)f2bf(a.w) << 16);
    o.z = f2bf(b.x) | ((unsigned)f2bf(b.y) << 16);
    o.w = f2bf(b.z) | ((unsigned)f2bf(b.w) << 16);
    *(uint4*)(dst + (size_t)i * 8) = o;
  }
}

// ---------------- bf16 GEMM, B^T layout, 128x128 tile, BK=32 (m97 structure) ----------------
template <int KTOT, bool GATHER, bool RELUOUT>
__global__ __launch_bounds__(256) void gemm_bt(const unsigned short* __restrict__ Abase,
                                               const int* __restrict__ seq, int seq_off,
                                               const unsigned short* __restrict__ Bmat,
                                               const float* __restrict__ bias,
                                               unsigned short* __restrict__ outb,
                                               float* __restrict__ outf,
                                               int out_row_off, int ldout) {
  __shared__ unsigned short As[128 * 32];
  __shared__ unsigned short Bs[128 * 32];
  __shared__ unsigned long long aoff[128];
  const int tid = threadIdx.x;
  const int m0 = blockIdx.x * 128, n0 = blockIdx.y * 128;

  if (tid < 128) {
    long long r;
    if (GATHER) r = (long long)seq[seq_off + m0 + tid] * KTOT;
    else        r = (long long)(m0 + tid) * KTOT;
    aoff[tid] = (unsigned long long)r;
  }
  __syncthreads();

  const int srow = tid >> 2;
  const int scol = (tid & 3) * 8;
  const int wave = tid >> 6;
  const int lane = tid & 63;
  const int wr = wave >> 1, wc = wave & 1;
  const int fr = lane & 15;
  const int fk = (lane >> 4) * 8;

  f32x4 acc[4][4] = {};

  for (int k0 = 0; k0 < KTOT; k0 += 32) {
#pragma unroll
    for (int i = 0; i < 2; ++i) {
      const unsigned short* ga = Abase + aoff[i * 64 + srow] + k0 + scol;
      __builtin_amdgcn_global_load_lds((const GAS void*)ga,
          (LAS void*)((char*)As + i * 4096 + wave * 1024), 16, 0, 0);
      const unsigned short* gb = Bmat + (size_t)(n0 + i * 64 + srow) * KTOT + k0 + scol;
      __builtin_amdgcn_global_load_lds((const GAS void*)gb,
          (LAS void*)((char*)Bs + i * 4096 + wave * 1024), 16, 0, 0);
    }
    __syncthreads();
    bf16x8 af[4], bfr[4];
#pragma unroll
    for (int m = 0; m < 4; ++m)
      af[m] = *(const bf16x8*)&As[(wr * 64 + m * 16 + fr) * 32 + fk];
#pragma unroll
    for (int n = 0; n < 4; ++n)
      bfr[n] = *(const bf16x8*)&Bs[(wc * 64 + n * 16 + fr) * 32 + fk];
#pragma unroll
    for (int m = 0; m < 4; ++m)
#pragma unroll
      for (int n = 0; n < 4; ++n)
        acc[m][n] = __builtin_amdgcn_mfma_f32_16x16x32_bf16(af[m], bfr[n], acc[m][n], 0, 0, 0);
    __syncthreads();
  }

  float bv[4];
#pragma unroll
  for (int n = 0; n < 4; ++n) bv[n] = bias[n0 + wc * 64 + n * 16 + fr];
#pragma unroll
  for (int m = 0; m < 4; ++m) {
#pragma unroll
    for (int n = 0; n < 4; ++n) {
#pragma unroll
      for (int j = 0; j < 4; ++j) {
        int rl = wr * 64 + m * 16 + ((lane >> 4) << 2) + j;
        int col = n0 + wc * 64 + n * 16 + fr;
        float v = acc[m][n][j] + bv[n];
        size_t off = (size_t)(out_row_off + m0 + rl) * ldout + col;
        if (RELUOUT) { v = fmaxf(v, 0.f); outb[off] = f2bf(v); }
        else outf[off] = v;
      }
    }
  }
}

// ---------------- residual add + LayerNorm ----------------
__global__ __launch_bounds__(256) void ln_kernel(float* __restrict__ xbuf,
                                                 const float* __restrict__ embed,
                                                 const int* __restrict__ seq,
                                                 const float* __restrict__ lnw,
                                                 const float* __restrict__ lnb) {
  int row = blockIdx.x * 4 + (threadIdx.x >> 6);
  int lane = threadIdx.x & 63;
  int c = lane * 8;
  int s = seq[row];
  float* xr = xbuf + (size_t)row * Hh;
  const float* hr = embed + (size_t)s * Hh;
  float4 f0 = *(const float4*)(xr + c), f1 = *(const float4*)(xr + c + 4);
  float4 h0 = *(const float4*)(hr + c), h1 = *(const float4*)(hr + c + 4);
  float x[8] = {f0.x + h0.x, f0.y + h0.y, f0.z + h0.z, f0.w + h0.w,
                f1.x + h1.x, f1.y + h1.y, f1.z + h1.z, f1.w + h1.w};
  float sm = 0.f, sq = 0.f;
#pragma unroll
  for (int u = 0; u < 8; ++u) { sm += x[u]; sq += x[u] * x[u]; }
#pragma unroll
  for (int m = 1; m < 64; m <<= 1) { sm += __shfl_xor(sm, m, 64); sq += __shfl_xor(sq, m, 64); }
  float mu = sm * (1.f / 512.f);
  float var = sq * (1.f / 512.f) - mu * mu;
  float rs = rsqrtf(var + EPSc);
  float y[8];
#pragma unroll
  for (int u = 0; u < 8; ++u) y[u] = (x[u] - mu) * rs * lnw[c + u] + lnb[c + u];
  *(float4*)(xr + c) = make_float4(y[0], y[1], y[2], y[3]);
  *(float4*)(xr + c + 4) = make_float4(y[4], y[5], y[6], y[7]);
}

// ---------------- TTT scan: 16 blocks x 1 wave; barrier-free, LDS-free ----------------
// Lane l owns columns 8l..8l+7 (k, W1 rows j=0..7) and rows 8l..8l+7 (v, W2, pred).
__global__ __launch_bounds__(64, 1) void ttt_kernel(const float* __restrict__ hidden,
                                                    const float* __restrict__ w1_0,
                                                    const float* __restrict__ b1_0,
                                                    const float* __restrict__ w2_0,
                                                    const float* __restrict__ b2_0,
                                                    float* __restrict__ ctx) {
  const int b = blockIdx.x;
  const int l = threadIdx.x;
  const int c0 = l * 8;
  const float* hb = hidden + (size_t)b * Ll * Hh;
  const float scale = 2.0f / 512.0f;

  f32x2 W1v[8][4];  // W1v[j][p] = W1[j][c0+2p .. c0+2p+1]
  f32x2 W2v[8][4];  // W2v[u][p] = W2[c0+u][2p .. 2p+1]
  float B1[8], B2[8];
#pragma unroll
  for (int j = 0; j < 8; ++j) {
    float4 a = *(const float4*)(w1_0 + (size_t)j * Hh + c0);
    float4 d = *(const float4*)(w1_0 + (size_t)j * Hh + c0 + 4);
    W1v[j][0] = f32x2{a.x, a.y}; W1v[j][1] = f32x2{a.z, a.w};
    W1v[j][2] = f32x2{d.x, d.y}; W1v[j][3] = f32x2{d.z, d.w};
    B1[j] = b1_0[j];
  }
#pragma unroll
  for (int u = 0; u < 8; ++u) {
    float4 a = *(const float4*)(w2_0 + (size_t)(c0 + u) * 8);
    float4 d = *(const float4*)(w2_0 + (size_t)(c0 + u) * 8 + 4);
    W2v[u][0] = f32x2{a.x, a.y}; W2v[u][1] = f32x2{a.z, a.w};
    W2v[u][2] = f32x2{d.x, d.y}; W2v[u][3] = f32x2{d.z, d.w};
  }
  {
    float4 e = *(const float4*)(b2_0 + c0);
    float4 f = *(const float4*)(b2_0 + c0 + 4);
    B2[0] = e.x; B2[1] = e.y; B2[2] = e.z; B2[3] = e.w;
    B2[4] = f.x; B2[5] = f.y; B2[6] = f.z; B2[7] = f.w;
  }

  f32x2 Kc[4];
  float Vs[8];
  const float* pk = hb + c0;        // key row 0
  const float* pv = hb + Hh + c0;   // val row 1
  {
    float4 a = *(const float4*)pk, d = *(const float4*)(pk + 4);
    Kc[0] = f32x2{a.x, a.y}; Kc[1] = f32x2{a.z, a.w};
    Kc[2] = f32x2{d.x, d.y}; Kc[3] = f32x2{d.z, d.w};
    float4 e = *(const float4*)pv, f = *(const float4*)(pv + 4);
    Vs[0] = e.x; Vs[1] = e.y; Vs[2] = e.z; Vs[3] = e.w;
    Vs[4] = f.x; Vs[5] = f.y; Vs[6] = f.z; Vs[7] = f.w;
  }

#pragma unroll 2
  for (int t = 0; t < 1023; ++t) {
    float4 ka, kb, va, vb;
    const bool pre = (t < 1022);
    if (pre) {  // prefetch next (k,v); latency hidden under this step's ~800cy of VALU
      ka = *(const float4*)(pk + 1024); kb = *(const float4*)(pk + 1028);
      va = *(const float4*)(pv + 1024); vb = *(const float4*)(pv + 1028);
    }

    // z_j = W1[j,:]@k + b1[j]; h = relu(z)
    float z[8], h[8];
#pragma unroll
    for (int j = 0; j < 8; ++j) {
      f32x2 acc = {0.f, 0.f};
#pragma unroll
      for (int p = 0; p < 4; ++p) acc = pk_fma(W1v[j][p], Kc[p], acc);
      float s = wsum_bcast(acc.x + acc.y);
      z[j] = s + B1[j];
      h[j] = fmaxf(z[j], 0.f);
    }
    f32x2 h2[4];
#pragma unroll
    for (int p = 0; p < 4; ++p) h2[p] = f32x2{h[2 * p], h[2 * p + 1]};

    // pred_i = W2[i,:]@h + b2_i ; d_i = (pred_i - v_i)*2/512   (i = c0+u, lane-local)
    float d_[8];
    f32x2 dd[8];
#pragma unroll
    for (int u = 0; u < 8; ++u) {
      f32x2 acc = {0.f, 0.f};
#pragma unroll
      for (int p = 0; p < 4; ++p) acc = pk_fma(W2v[u][p], h2[p], acc);
      float pred = acc.x + acc.y + B2[u];
      float dv = (pred - Vs[u]) * scale;
      d_[u] = dv;
      dd[u] = f32x2{dv, dv};
    }

    // dh_j = sum_i W2[i][j]*d_i  (OLD W2), dz_j = dh_j * relu'(z_j)
    f32x2 dhp[4] = {{0.f, 0.f}, {0.f, 0.f}, {0.f, 0.f}, {0.f, 0.f}};
#pragma unroll
    for (int u = 0; u < 8; ++u)
#pragma unroll
      for (int p = 0; p < 4; ++p) dhp[p] = pk_fma(W2v[u][p], dd[u], dhp[p]);
    float dz[8];
#pragma unroll
    for (int p = 0; p < 4; ++p) {
      float s0 = wsum_bcast(dhp[p].x);
      float s1 = wsum_bcast(dhp[p].y);
      dz[2 * p]     = (z[2 * p]     > 0.f) ? s0 : 0.f;
      dz[2 * p + 1] = (z[2 * p + 1] > 0.f) ? s1 : 0.f;
    }

    // W2 -= lr * d h^T ; b2 -= lr*d
#pragma unroll
    for (int u = 0; u < 8; ++u) {
      float g = -LRc * d_[u];
      f32x2 gv = {g, g};
#pragma unroll
      for (int p = 0; p < 4; ++p) W2v[u][p] = pk_fma(gv, h2[p], W2v[u][p]);
      B2[u] = fmaf(-LRc, d_[u], B2[u]);
    }
    // W1 -= lr * dz k^T ; b1 -= lr*dz
#pragma unroll
    for (int j = 0; j < 8; ++j) {
      float g = -LRc * dz[j];
      f32x2 gv = {g, g};
#pragma unroll
      for (int p = 0; p < 4; ++p) W1v[j][p] = pk_fma(gv, Kc[p], W1v[j][p]);
      B1[j] = fmaf(-LRc, dz[j], B1[j]);
    }

    if (pre) {
      Kc[0] = f32x2{ka.x, ka.y}; Kc[1] = f32x2{ka.z, ka.w};
      Kc[2] = f32x2{kb.x, kb.y}; Kc[3] = f32x2{kb.z, kb.w};
      Vs[0] = va.x; Vs[1] = va.y; Vs[2] = va.z; Vs[3] = va.w;
      Vs[4] = vb.x; Vs[5] = vb.y; Vs[6] = vb.z; Vs[7] = vb.w;
      pk += 1024; pv += 1024;
    }
  }

  // query = hidden row L-1; out_i = W2[i,:]@relu(W1@q+b1) + b2_i
  {
    const float* pq = hb + (size_t)(Ll - 1) * Hh + c0;
    float4 a = *(const float4*)pq, d = *(const float4*)(pq + 4);
    f32x2 Q[4] = {f32x2{a.x, a.y}, f32x2{a.z, a.w}, f32x2{d.x, d.y}, f32x2{d.z, d.w}};
    float h[8];
#pragma unroll
    for (int j = 0; j < 8; ++j) {
      f32x2 acc = {0.f, 0.f};
#pragma unroll
      for (int p = 0; p < 4; ++p) acc = pk_fma(W1v[j][p], Q[p], acc);
      float s = wsum_bcast(acc.x + acc.y);
      h[j] = fmaxf(s + B1[j], 0.f);
    }
    f32x2 h2[4];
#pragma unroll
    for (int p = 0; p < 4; ++p) h2[p] = f32x2{h[2 * p], h[2 * p + 1]};
    float o[8];
#pragma unroll
    for (int u = 0; u < 8; ++u) {
      f32x2 acc = {0.f, 0.f};
#pragma unroll
      for (int p = 0; p < 4; ++p) acc = pk_fma(W2v[u][p], h2[p], acc);
      o[u] = acc.x + acc.y + B2[u];
    }
    float* cp = ctx + (size_t)b * Hh + c0;
    *(float4*)cp = make_float4(o[0], o[1], o[2], o[3]);
    *(float4*)(cp + 4) = make_float4(o[4], o[5], o[6], o[7]);
  }
}

// ---------------- head: out[b,v] = ctx[b,:] @ out_w[v,:] + out_b[v] ----------------
__global__ __launch_bounds__(256) void out_kernel(const float* __restrict__ ctx,
                                                  const float* __restrict__ outw,
                                                  const float* __restrict__ outb_,
                                                  float* __restrict__ out) {
  __shared__ float cs[16 * 516];
  int tid = threadIdx.x;
#pragma unroll
  for (int r = 0; r < 32; ++r) {
    int idx = r * 256 + tid;
    cs[(idx >> 9) * 516 + (idx & 511)] = ctx[idx];
  }
  __syncthreads();
  int v = blockIdx.x * 16 + (tid >> 4);
  int b = tid & 15;
  const float4* wr = (const float4*)(outw + (size_t)v * 512);
  const float4* cr = (const float4*)(cs + b * 516);
  float acc = 0.f;
#pragma unroll 8
  for (int k = 0; k < 128; ++k) {
    float4 wv = wr[k];
    float4 cv = cr[k];
    acc += wv.x * cv.x + wv.y * cv.y + wv.z * cv.z + wv.w * cv.w;
  }
  out[(size_t)b * 32000 + v] = acc + outb_[v];
}

extern "C" void kernel_launch(void* const* d_in, const int* in_sizes, int n_in,
                              void* d_out, int out_size, void* d_ws, size_t ws_size,
                              hipStream_t stream) {
  const int*   seq    = (const int*)d_in[0];
  const float* embed  = (const float*)d_in[1];
  const float* enc_w1 = (const float*)d_in[2];
  const float* enc_b1 = (const float*)d_in[3];
  const float* enc_w2 = (const float*)d_in[4];
  const float* enc_b2 = (const float*)d_in[5];
  const float* ln_w   = (const float*)d_in[6];
  const float* ln_b   = (const float*)d_in[7];
  const float* mlp_w1 = (const float*)d_in[8];
  const float* mlp_b1 = (const float*)d_in[9];
  const float* mlp_w2 = (const float*)d_in[10];
  const float* mlp_b2 = (const float*)d_in[11];
  const float* out_w  = (const float*)d_in[12];
  const float* out_b  = (const float*)d_in[13];
  float* out = (float*)d_out;

  char* ws = (char*)d_ws;
  float*          xbuf = (float*)(ws + OFF_X);
  unsigned short* ebf  = (unsigned short*)(ws + OFF_EBF);
  unsigned short* w1bf = (unsigned short*)(ws + OFF_W1BF);
  unsigned short* w2bf = (unsigned short*)(ws + OFF_W2BF);
  float*          ctx  = (float*)(ws + OFF_CTX);
  unsigned short* ff1  = (unsigned short*)(ws + OFF_FF1);

  const int cand[4] = {1, 2, 4, 8};
  int nc = 8;
  for (int ci = 0; ci < 4; ++ci) {
    if (OFF_FF1 + (size_t)(Mtot / cand[ci]) * H2 * 2 <= ws_size) { nc = cand[ci]; break; }
  }

  cvt_bf16_kernel<<<2048, 256, 0, stream>>>(embed, ebf, Vv * Hh / 8);
  cvt_bf16_kernel<<<256, 256, 0, stream>>>(enc_w1, w1bf, H2 * Hh / 8);
  cvt_bf16_kernel<<<256, 256, 0, stream>>>(enc_w2, w2bf, Hh * H2 / 8);

  const int Mc = Mtot / nc;
  for (int c = 0; c < nc; ++c) {
    const int m0 = c * Mc;
    gemm_bt<512, true, true><<<dim3(Mc / 128, 8), 256, 0, stream>>>(
        ebf, seq, m0, w1bf, enc_b1, ff1, nullptr, 0, H2);
    gemm_bt<1024, false, false><<<dim3(Mc / 128, 4), 256, 0, stream>>>(
        ff1, nullptr, 0, w2bf, enc_b2, nullptr, xbuf, m0, Hh);
  }
  ln_kernel<<<Mtot / 4, 256, 0, stream>>>(xbuf, embed, seq, ln_w, ln_b);
  ttt_kernel<<<Bb, 64, 0, stream>>>(xbuf, mlp_w1, mlp_b1, mlp_w2, mlp_b2, ctx);
  out_kernel<<<Vv / 16, 256, 0, stream>>>(ctx, out_w, out_b, out);
}